// Round 1
// baseline (555.344 us; speedup 1.0000x reference)
//
#include <hip/hip_runtime.h>

#define B 128
#define N 65536
#define D 512
#define K 5
#define M 256            // D * RATIO
#define GTILE 256        // gallery rows per block in kernel1
#define NBLK1 (N / GTILE)   // 256 blocks
#define PASSG 64         // gallery rows per pass
#define NPASS (GTILE / PASSG)
#define DC 32            // D-chunk
#define NCHUNK (D / DC)
#define TSTR 36          // padded LDS stride (floats) for t tile
#define GSTR 36
#define SSTR 65          // padded stride for scores tile

__device__ __forceinline__ void top5_insert(float v, int gi, float tv[K], int ti[K]) {
    // descending by value, ties broken by lower index (matches lax.top_k)
    if (v > tv[K - 1] || (v == tv[K - 1] && gi < ti[K - 1])) {
        tv[K - 1] = v; ti[K - 1] = gi;
        #pragma unroll
        for (int k = K - 1; k > 0; --k) {
            bool sw = (tv[k] > tv[k - 1]) || (tv[k] == tv[k - 1] && ti[k] < ti[k - 1]);
            if (sw) {
                float fv = tv[k]; tv[k] = tv[k - 1]; tv[k - 1] = fv;
                int fi = ti[k]; ti[k] = ti[k - 1]; ti[k - 1] = fi;
            }
        }
    }
}

// Kernel 1: per gallery-chunk, compute scores dot(t_f[b], g[j]) * rsqrt(||g_j||^2)
// for all 128 b, keep per-b running top-5 within the block's 256 gallery rows.
__global__ __launch_bounds__(512) void k1_sims_topk(const float* __restrict__ t_f,
                                                    const float* __restrict__ gal,
                                                    float2* __restrict__ partial) {
    __shared__ float tT[B * TSTR];       // 18432 B
    __shared__ float gT[PASSG * GSTR];   // 9216 B
    __shared__ float scaleS[PASSG];
    __shared__ float scoresS[B * SSTR];  // 33280 B

    const int tid = threadIdx.x;
    const int blk = blockIdx.x;
    const int b0 = (tid >> 4) * 4;   // 0..124
    const int g0 = (tid & 15) * 4;   // 0..60

    float tv[K]; int ti[K];
    #pragma unroll
    for (int k = 0; k < K; ++k) { tv[k] = -1e30f; ti[k] = 0x7fffffff; }

    for (int pass = 0; pass < NPASS; ++pass) {
        const int grow0 = blk * GTILE + pass * PASSG;
        float acc[4][4];
        #pragma unroll
        for (int i = 0; i < 4; ++i)
            #pragma unroll
            for (int j = 0; j < 4; ++j) acc[i][j] = 0.0f;
        float nrm = 0.0f;

        for (int dc = 0; dc < NCHUNK; ++dc) {
            __syncthreads();
            // stage t chunk [128][32]
            #pragma unroll
            for (int it = 0; it < 2; ++it) {
                int q = tid + 512 * it;          // 0..1023
                int row = q >> 3, c4 = q & 7;
                float4 v = *reinterpret_cast<const float4*>(t_f + (size_t)row * D + dc * DC + c4 * 4);
                *reinterpret_cast<float4*>(tT + row * TSTR + c4 * 4) = v;
            }
            // stage g chunk [64][32]
            {
                int row = tid >> 3, c4 = tid & 7;  // 512 threads -> 512 float4
                float4 v = *reinterpret_cast<const float4*>(gal + (size_t)(grow0 + row) * D + dc * DC + c4 * 4);
                *reinterpret_cast<float4*>(gT + row * GSTR + c4 * 4) = v;
            }
            __syncthreads();
            // gallery row norms (threads 0..63)
            if (tid < PASSG) {
                #pragma unroll
                for (int d4 = 0; d4 < 8; ++d4) {
                    float4 v = *reinterpret_cast<const float4*>(gT + tid * GSTR + d4 * 4);
                    nrm = fmaf(v.x, v.x, nrm);
                    nrm = fmaf(v.y, v.y, nrm);
                    nrm = fmaf(v.z, v.z, nrm);
                    nrm = fmaf(v.w, v.w, nrm);
                }
            }
            // FMA: 4 b-rows x 4 g-rows per thread
            #pragma unroll
            for (int d4 = 0; d4 < 8; ++d4) {
                float4 gb[4];
                #pragma unroll
                for (int j = 0; j < 4; ++j)
                    gb[j] = *reinterpret_cast<const float4*>(gT + (g0 + j) * GSTR + d4 * 4);
                #pragma unroll
                for (int i = 0; i < 4; ++i) {
                    float4 ta = *reinterpret_cast<const float4*>(tT + (b0 + i) * TSTR + d4 * 4);
                    #pragma unroll
                    for (int j = 0; j < 4; ++j) {
                        acc[i][j] = fmaf(ta.x, gb[j].x, acc[i][j]);
                        acc[i][j] = fmaf(ta.y, gb[j].y, acc[i][j]);
                        acc[i][j] = fmaf(ta.z, gb[j].z, acc[i][j]);
                        acc[i][j] = fmaf(ta.w, gb[j].w, acc[i][j]);
                    }
                }
            }
        }
        if (tid < PASSG) scaleS[tid] = 1.0f / fmaxf(sqrtf(nrm), 1e-12f);
        __syncthreads();
        #pragma unroll
        for (int i = 0; i < 4; ++i)
            #pragma unroll
            for (int j = 0; j < 4; ++j)
                scoresS[(b0 + i) * SSTR + (g0 + j)] = acc[i][j] * scaleS[g0 + j];
        __syncthreads();
        if (tid < B) {
            const int b = tid;
            for (int g = 0; g < PASSG; ++g) {
                float v = scoresS[b * SSTR + g];
                top5_insert(v, grow0 + g, tv, ti);
            }
        }
        // next pass's first __syncthreads() protects scoresS from overwrite ordering
    }
    if (tid < B) {
        #pragma unroll
        for (int k = 0; k < K; ++k)
            partial[((size_t)blk * B + tid) * K + k] = make_float2(tv[k], __int_as_float(ti[k]));
    }
}

// Kernel 2: merge 256 partial top-5 lists per batch row -> global top-5 indices.
// Also (block 0) initialize the 512-bit AND bitmap to all-ones.
__global__ __launch_bounds__(256) void k2_merge(const float2* __restrict__ partial,
                                               int* __restrict__ top_idx,
                                               unsigned long long* __restrict__ mask64) {
    __shared__ float2 cand[NBLK1 * K];  // 256 threads x 5
    const int b = blockIdx.x;
    const int p = threadIdx.x;
    if (b == 0 && p < (D / 64)) mask64[p] = ~0ull;

    float mv[K]; int mi[K];
    #pragma unroll
    for (int k = 0; k < K; ++k) {
        float2 c = partial[((size_t)p * B + b) * K + k];
        mv[k] = c.x; mi[k] = __float_as_int(c.y);
        cand[p * K + k] = c;
    }
    __syncthreads();
    for (int s = 128; s >= 1; s >>= 1) {
        if (p < s) {
            #pragma unroll
            for (int k = 0; k < K; ++k) {
                float2 c = cand[(p + s) * K + k];
                top5_insert(c.x, __float_as_int(c.y), mv, mi);
            }
            #pragma unroll
            for (int k = 0; k < K; ++k)
                cand[p * K + k] = make_float2(mv[k], __int_as_float(mi[k]));
        }
        __syncthreads();
    }
    if (p == 0) {
        #pragma unroll
        for (int k = 0; k < K; ++k) top_idx[b * K + k] = mi[k];
    }
}

// Kernel 3: for each (b,k) row, membership = channel rank < M under stable
// ascending sort of |gallery[row,c] * s_f[b,c]| (norms are per-row constants:
// ordering identical to the reference's normalized products). AND into bitmap.
__global__ __launch_bounds__(512) void k3_member(const float* __restrict__ s_f,
                                                 const float* __restrict__ gal,
                                                 const int* __restrict__ top_idx,
                                                 unsigned long long* __restrict__ mask64) {
    __shared__ float pS[D];
    const int c = threadIdx.x;
    const int bk = blockIdx.x;
    const int b = bk / K;
    const int row = top_idx[bk];
    float pv = fabsf(gal[(size_t)row * D + c] * s_f[(size_t)b * D + c]);
    pS[c] = pv;
    __syncthreads();
    int cnt = 0;
    for (int c2 = 0; c2 < D; ++c2) {
        float o = pS[c2];
        cnt += (o < pv || (o == pv && c2 < c)) ? 1 : 0;
    }
    bool member = cnt < M;  // in bottom-m set
    unsigned long long bm = __ballot(member);
    if ((c & 63) == 0) atomicAnd(&mask64[c >> 6], bm);
}

// Kernel 4: mask[c] = zero_out[c] ? 0 : 1
__global__ __launch_bounds__(512) void k4_mask(const unsigned long long* __restrict__ mask64,
                                               float* __restrict__ out) {
    int c = threadIdx.x;
    out[c] = ((mask64[c >> 6] >> (c & 63)) & 1ull) ? 0.0f : 1.0f;
}

extern "C" void kernel_launch(void* const* d_in, const int* in_sizes, int n_in,
                              void* d_out, int out_size, void* d_ws, size_t ws_size,
                              hipStream_t stream) {
    (void)in_sizes; (void)n_in; (void)out_size; (void)ws_size;
    const float* s_f = (const float*)d_in[0];
    const float* t_f = (const float*)d_in[1];
    const float* gal = (const float*)d_in[2];
    float* out = (float*)d_out;

    char* ws = (char*)d_ws;
    size_t off_partial = 0;
    size_t sz_partial = (size_t)NBLK1 * B * K * sizeof(float2);   // 1,310,720 B
    size_t off_topidx = off_partial + sz_partial;                 // 8-aligned
    size_t sz_topidx = (size_t)B * K * sizeof(int);               // 2,560 B
    size_t off_mask = off_topidx + sz_topidx;                     // 8-aligned

    float2* partial = (float2*)(ws + off_partial);
    int* top_idx = (int*)(ws + off_topidx);
    unsigned long long* mask64 = (unsigned long long*)(ws + off_mask);

    hipLaunchKernelGGL(k1_sims_topk, dim3(NBLK1), dim3(512), 0, stream, t_f, gal, partial);
    hipLaunchKernelGGL(k2_merge, dim3(B), dim3(256), 0, stream, partial, top_idx, mask64);
    hipLaunchKernelGGL(k3_member, dim3(B * K), dim3(512), 0, stream, s_f, gal, top_idx, mask64);
    hipLaunchKernelGGL(k4_mask, dim3(1), dim3(512), 0, stream, mask64, out);
}

// Round 2
// 192.391 us; speedup vs baseline: 2.8865x; 2.8865x over previous
//
#include <hip/hip_runtime.h>

#define B 128
#define N 65536
#define D 512
#define K 5
#define M 256              // D * RATIO
#define BG 128             // gallery rows per block (kernel1)
#define NBLK1 (N / BG)     // 512 blocks
#define BK 64              // D-chunk per staging pass
#define NCH (D / BK)       // 8
#define SSTR 66            // scores LDS stride

typedef __attribute__((ext_vector_type(8))) short short8;
typedef __attribute__((ext_vector_type(4))) float f32x4;

__device__ __forceinline__ unsigned short f2bf(float x) {
    // round-to-nearest-even bf16 truncation (normal inputs)
    unsigned int u = __float_as_uint(x);
    unsigned int lsb = (u >> 16) & 1u;
    u += 0x7fffu + lsb;
    return (unsigned short)(u >> 16);
}

__device__ __forceinline__ void top5_insert(float v, int gi, float tv[K], int ti[K]) {
    // descending by value, ties broken by lower index (matches lax.top_k)
    if (v > tv[K - 1] || (v == tv[K - 1] && gi < ti[K - 1])) {
        tv[K - 1] = v; ti[K - 1] = gi;
        #pragma unroll
        for (int k = K - 1; k > 0; --k) {
            bool sw = (tv[k] > tv[k - 1]) || (tv[k] == tv[k - 1] && ti[k] < ti[k - 1]);
            if (sw) {
                float fv = tv[k]; tv[k] = tv[k - 1]; tv[k - 1] = fv;
                int fi = ti[k]; ti[k] = ti[k - 1]; ti[k - 1] = fi;
            }
        }
    }
}

// Kernel 1: bf16 MFMA sims. Block: 128 b x 128 gallery rows, 8 waves (4b x 2g),
// wave tile 32b x 64g. fp32 -> bf16 convert during reg-staged LDS writes with
// T2 XOR swizzle (byte ^= (row&7)<<4) so ds_read_b128 fragment loads are
// conflict-free. Gallery row norms accumulated during staging (per-row scale
// applied to MFMA output; t-norm is a positive per-b constant -> rank-invariant).
__global__ __launch_bounds__(512) void k1_sims_topk(const float* __restrict__ t_f,
                                                    const float* __restrict__ gal,
                                                    float2* __restrict__ partial) {
    __shared__ unsigned short tA[B * BK];    // 16384 B, swizzled bf16 [128][64]
    __shared__ unsigned short gB[BG * BK];   // 16384 B, swizzled bf16 [128][64]
    __shared__ float normP[BG * 16];         // 8192 B
    __shared__ float scaleS[BG];             // 512 B
    __shared__ float scoresS[B * SSTR];      // 33792 B   (total 75264 B -> 2 blk/CU)

    const int tid = threadIdx.x;
    const int blk = blockIdx.x;
    const int lane = tid & 63;
    const int w = tid >> 6;
    const int wb = w >> 1;     // 0..3 : b-block of 32
    const int wg = w & 1;      // 0..1 : g-block of 64

    f32x4 acc[2][4];
    #pragma unroll
    for (int m = 0; m < 2; ++m)
        #pragma unroll
        for (int n = 0; n < 4; ++n) acc[m][n] = (f32x4)0.0f;

    float nrm[4] = {0.f, 0.f, 0.f, 0.f};
    const size_t grow0 = (size_t)blk * BG;

    for (int ch = 0; ch < NCH; ++ch) {
        __syncthreads();
        // stage t chunk [128][64] fp32 -> bf16 swizzled
        #pragma unroll
        for (int it = 0; it < 4; ++it) {
            int q = tid + it * 512;          // 0..2047, coalesced
            int row = q >> 4, f4c = q & 15;
            float4 v = *reinterpret_cast<const float4*>(t_f + (size_t)row * D + ch * BK + f4c * 4);
            ushort4 p;
            p.x = f2bf(v.x); p.y = f2bf(v.y); p.z = f2bf(v.z); p.w = f2bf(v.w);
            int byte = row * 128 + f4c * 8;
            byte ^= (row & 7) << 4;
            *reinterpret_cast<ushort4*>(reinterpret_cast<char*>(tA) + byte) = p;
        }
        // stage g chunk, accumulate row sumsq
        #pragma unroll
        for (int it = 0; it < 4; ++it) {
            int q = tid + it * 512;
            int row = q >> 4, f4c = q & 15;
            float4 v = *reinterpret_cast<const float4*>(gal + (grow0 + row) * D + ch * BK + f4c * 4);
            nrm[it] = fmaf(v.x, v.x, nrm[it]);
            nrm[it] = fmaf(v.y, v.y, nrm[it]);
            nrm[it] = fmaf(v.z, v.z, nrm[it]);
            nrm[it] = fmaf(v.w, v.w, nrm[it]);
            ushort4 p;
            p.x = f2bf(v.x); p.y = f2bf(v.y); p.z = f2bf(v.z); p.w = f2bf(v.w);
            int byte = row * 128 + f4c * 8;
            byte ^= (row & 7) << 4;
            *reinterpret_cast<ushort4*>(reinterpret_cast<char*>(gB) + byte) = p;
        }
        __syncthreads();
        // 2 k-halves of 32: load frags (swizzled ds_read_b128) + 8 MFMA each
        #pragma unroll
        for (int kh = 0; kh < 2; ++kh) {
            const int koff = kh * 64 + (lane >> 4) * 16;   // byte offset of lane's 8 bf16
            short8 a[2], bfr[4];
            #pragma unroll
            for (int m = 0; m < 2; ++m) {
                int row = wb * 32 + m * 16 + (lane & 15);
                int byte = row * 128 + koff;
                byte ^= (row & 7) << 4;
                a[m] = *reinterpret_cast<const short8*>(reinterpret_cast<const char*>(tA) + byte);
            }
            #pragma unroll
            for (int n = 0; n < 4; ++n) {
                int row = wg * 64 + n * 16 + (lane & 15);
                int byte = row * 128 + koff;
                byte ^= (row & 7) << 4;
                bfr[n] = *reinterpret_cast<const short8*>(reinterpret_cast<const char*>(gB) + byte);
            }
            #pragma unroll
            for (int m = 0; m < 2; ++m)
                #pragma unroll
                for (int n = 0; n < 4; ++n)
                    acc[m][n] = __builtin_amdgcn_mfma_f32_16x16x32_bf16(a[m], bfr[n], acc[m][n], 0, 0, 0);
        }
    }

    // gallery norms: thread's 4 rows were fixed across chunks
    __syncthreads();
    #pragma unroll
    for (int it = 0; it < 4; ++it) {
        int q = tid + it * 512;
        normP[(q >> 4) * 16 + (tid & 15)] = nrm[it];
    }
    __syncthreads();
    if (tid < BG) {
        float s = 0.f;
        #pragma unroll
        for (int i = 0; i < 16; ++i) s += normP[tid * 16 + i];
        scaleS[tid] = 1.0f / fmaxf(sqrtf(s), 1e-12f);
    }
    __syncthreads();

    // top-5 over the block's 128 g rows, two 64-g phases through scoresS
    float tv[K]; int ti[K];
    #pragma unroll
    for (int k = 0; k < K; ++k) { tv[k] = -1e30f; ti[k] = 0x7fffffff; }

    for (int p = 0; p < 2; ++p) {
        if (wg == p) {
            #pragma unroll
            for (int n = 0; n < 4; ++n) {
                int gl = n * 16 + (lane & 15);           // 0..63 within phase
                float sc = scaleS[p * 64 + gl];
                #pragma unroll
                for (int m = 0; m < 2; ++m) {
                    int brow = wb * 32 + m * 16 + (lane >> 4) * 4;  // C/D: row=(l>>4)*4+r
                    #pragma unroll
                    for (int r = 0; r < 4; ++r)
                        scoresS[(brow + r) * SSTR + gl] = acc[m][n][r] * sc;
                }
            }
        }
        __syncthreads();
        if (tid < B) {
            #pragma unroll 8
            for (int g = 0; g < 64; ++g)
                top5_insert(scoresS[tid * SSTR + g], blk * BG + p * 64 + g, tv, ti);
        }
        __syncthreads();
    }
    if (tid < B) {
        #pragma unroll
        for (int k = 0; k < K; ++k)
            partial[((size_t)blk * B + tid) * K + k] = make_float2(tv[k], __int_as_float(ti[k]));
    }
}

// Kernel 2: merge 512 partial top-5 lists per batch row -> global top-5 indices.
// Block 0 also initializes the 512-bit AND bitmap.
__global__ __launch_bounds__(512) void k2_merge(const float2* __restrict__ partial,
                                               int* __restrict__ top_idx,
                                               unsigned long long* __restrict__ mask64) {
    __shared__ float2 cand[NBLK1 * K];  // 20480 B
    const int b = blockIdx.x;
    const int p = threadIdx.x;
    if (b == 0 && p < (D / 64)) mask64[p] = ~0ull;

    float mv[K]; int mi[K];
    #pragma unroll
    for (int k = 0; k < K; ++k) {
        float2 c = partial[((size_t)p * B + b) * K + k];
        mv[k] = c.x; mi[k] = __float_as_int(c.y);
        cand[p * K + k] = c;
    }
    __syncthreads();
    for (int s = NBLK1 / 2; s >= 1; s >>= 1) {
        if (p < s) {
            #pragma unroll
            for (int k = 0; k < K; ++k) {
                float2 c = cand[(p + s) * K + k];
                top5_insert(c.x, __float_as_int(c.y), mv, mi);
            }
            #pragma unroll
            for (int k = 0; k < K; ++k)
                cand[p * K + k] = make_float2(mv[k], __int_as_float(mi[k]));
        }
        __syncthreads();
    }
    if (p == 0) {
        #pragma unroll
        for (int k = 0; k < K; ++k) top_idx[b * K + k] = mi[k];
    }
}

// Kernel 3: rank-by-counting membership (bottom-m of |gal[row,c]*s_f[b,c]|;
// per-row norms are positive constants -> same ordering as the reference's
// normalized products), AND into bitmap.
__global__ __launch_bounds__(512) void k3_member(const float* __restrict__ s_f,
                                                 const float* __restrict__ gal,
                                                 const int* __restrict__ top_idx,
                                                 unsigned long long* __restrict__ mask64) {
    __shared__ float pS[D];
    const int c = threadIdx.x;
    const int bk = blockIdx.x;
    const int b = bk / K;
    const int row = top_idx[bk];
    float pv = fabsf(gal[(size_t)row * D + c] * s_f[(size_t)b * D + c]);
    pS[c] = pv;
    __syncthreads();
    int cnt = 0;
    #pragma unroll 8
    for (int c2 = 0; c2 < D; ++c2) {
        float o = pS[c2];
        cnt += (o < pv || (o == pv && c2 < c)) ? 1 : 0;
    }
    bool member = cnt < M;  // in bottom-m set
    unsigned long long bm = __ballot(member);
    if ((c & 63) == 0) atomicAnd(&mask64[c >> 6], bm);
}

// Kernel 4: mask[c] = zero_out[c] ? 0 : 1
__global__ __launch_bounds__(512) void k4_mask(const unsigned long long* __restrict__ mask64,
                                               float* __restrict__ out) {
    int c = threadIdx.x;
    out[c] = ((mask64[c >> 6] >> (c & 63)) & 1ull) ? 0.0f : 1.0f;
}

extern "C" void kernel_launch(void* const* d_in, const int* in_sizes, int n_in,
                              void* d_out, int out_size, void* d_ws, size_t ws_size,
                              hipStream_t stream) {
    (void)in_sizes; (void)n_in; (void)out_size; (void)ws_size;
    const float* s_f = (const float*)d_in[0];
    const float* t_f = (const float*)d_in[1];
    const float* gal = (const float*)d_in[2];
    float* out = (float*)d_out;

    char* ws = (char*)d_ws;
    size_t off_partial = 0;
    size_t sz_partial = (size_t)NBLK1 * B * K * sizeof(float2);   // 2,621,440 B
    size_t off_topidx = off_partial + sz_partial;
    size_t sz_topidx = (size_t)B * K * sizeof(int);
    size_t off_mask = off_topidx + sz_topidx;

    float2* partial = (float2*)(ws + off_partial);
    int* top_idx = (int*)(ws + off_topidx);
    unsigned long long* mask64 = (unsigned long long*)(ws + off_mask);

    hipLaunchKernelGGL(k1_sims_topk, dim3(NBLK1), dim3(512), 0, stream, t_f, gal, partial);
    hipLaunchKernelGGL(k2_merge, dim3(B), dim3(512), 0, stream, partial, top_idx, mask64);
    hipLaunchKernelGGL(k3_member, dim3(B * K), dim3(512), 0, stream, s_f, gal, top_idx, mask64);
    hipLaunchKernelGGL(k4_mask, dim3(1), dim3(512), 0, stream, mask64, out);
}

// Round 3
// 175.875 us; speedup vs baseline: 3.1576x; 1.0939x over previous
//
#include <hip/hip_runtime.h>

#define B 128
#define N 65536
#define D 512
#define K 5
#define M 256              // D * RATIO
#define BG 128             // gallery rows per block (kernel1)
#define NBLK1 (N / BG)     // 512 blocks
#define BK 64              // D-chunk per staging pass
#define NCH (D / BK)       // 8
#define SSTR 66            // scores LDS stride

typedef __attribute__((ext_vector_type(8))) short short8;
typedef __attribute__((ext_vector_type(4))) float f32x4;

// pack two fp32 -> one u32 of 2 bf16 (truncation) via v_perm_b32: 1 inst/pair.
// Ranking-safe: bf16 trunc error ~2^-8 rel, sim gap 5th/6th ~2e-3 >> dot error.
__device__ __forceinline__ unsigned int pack_bf2(float lo, float hi) {
    return __builtin_amdgcn_perm(__float_as_uint(hi), __float_as_uint(lo), 0x07060302u);
}

__device__ __forceinline__ void top5_insert(float v, int gi, float tv[K], int ti[K]) {
    // descending by value, ties broken by lower index (matches lax.top_k)
    if (v > tv[K - 1] || (v == tv[K - 1] && gi < ti[K - 1])) {
        tv[K - 1] = v; ti[K - 1] = gi;
        #pragma unroll
        for (int k = K - 1; k > 0; --k) {
            bool sw = (tv[k] > tv[k - 1]) || (tv[k] == tv[k - 1] && ti[k] < ti[k - 1]);
            if (sw) {
                float fv = tv[k]; tv[k] = tv[k - 1]; tv[k - 1] = fv;
                int fi = ti[k]; ti[k] = ti[k - 1]; ti[k - 1] = fi;
            }
        }
    }
}

// Kernel 0: convert t_f (128x512 fp32) -> bf16 once. L2-resident thereafter.
__global__ __launch_bounds__(256) void k0_cvt_t(const float* __restrict__ t_f,
                                                unsigned int* __restrict__ t_bf) {
    int i = blockIdx.x * 256 + threadIdx.x;   // float4 index, 16384 total
    float4 v = reinterpret_cast<const float4*>(t_f)[i];
    uint2 p;
    p.x = pack_bf2(v.x, v.y);
    p.y = pack_bf2(v.z, v.w);
    reinterpret_cast<uint2*>(t_bf)[i] = p;
}

// Kernel 1: bf16 MFMA sims, 128b x 128g per block, 8 waves (4b x 2g).
// Reg-prefetched staging (next chunk's global loads issued before current MFMA),
// T2 XOR-swizzled LDS, v_perm bf16 packing, 512-thread-parallel top-5.
__global__ __launch_bounds__(512, 4) void k1_sims_topk(const unsigned int* __restrict__ t_bf,
                                                       const float* __restrict__ gal,
                                                       float2* __restrict__ partial) {
    __shared__ unsigned short tA[B * BK];    // 16384 B swizzled bf16 [128][64]
    __shared__ unsigned short gB[BG * BK];   // 16384 B swizzled bf16 [128][64]
    __shared__ float normP[BG * 16];         // 8192 B
    __shared__ float scaleS[BG];             // 512 B
    __shared__ float scoresS[B * SSTR];      // 33792 B  (total 75264 -> 2 blk/CU)

    const int tid = threadIdx.x;
    const int blk = blockIdx.x;
    const int lane = tid & 63;
    const int w = tid >> 6;
    const int wb = w >> 1;     // 0..3 : b-block of 32
    const int wg = w & 1;      // 0..1 : g-block of 64
    const size_t grow0 = (size_t)blk * BG;

    const int t_row0 = tid >> 3;   // + it*64, it<2
    const int t_c8 = tid & 7;      // col-group of 8 bf16 (16 B)
    const int g_row0 = tid >> 4;   // + it*32, it<4
    const int g_f4c = tid & 15;    // col-group of 4 fp32

    f32x4 acc[2][4];
    #pragma unroll
    for (int m = 0; m < 2; ++m)
        #pragma unroll
        for (int n = 0; n < 4; ++n) acc[m][n] = (f32x4)0.0f;

    uint4 tReg[2];
    float4 gReg[4];

    // prefetch chunk 0
    #pragma unroll
    for (int it = 0; it < 2; ++it)
        tReg[it] = *reinterpret_cast<const uint4*>(t_bf + (size_t)(t_row0 + it * 64) * (D / 2) + t_c8 * 4);
    #pragma unroll
    for (int it = 0; it < 4; ++it)
        gReg[it] = *reinterpret_cast<const float4*>(gal + (grow0 + g_row0 + it * 32) * D + g_f4c * 4);

    float nrm[4] = {0.f, 0.f, 0.f, 0.f};

    for (int ch = 0; ch < NCH; ++ch) {
        __syncthreads();   // prev MFMA reads done; LDS free
        // write staged regs -> LDS (swizzled)
        #pragma unroll
        for (int it = 0; it < 2; ++it) {
            int row = t_row0 + it * 64;
            int byte = row * 128 + t_c8 * 16;
            byte ^= (row & 7) << 4;
            *reinterpret_cast<uint4*>(reinterpret_cast<char*>(tA) + byte) = tReg[it];
        }
        #pragma unroll
        for (int it = 0; it < 4; ++it) {
            float4 v = gReg[it];
            nrm[it] = fmaf(v.x, v.x, nrm[it]);
            nrm[it] = fmaf(v.y, v.y, nrm[it]);
            nrm[it] = fmaf(v.z, v.z, nrm[it]);
            nrm[it] = fmaf(v.w, v.w, nrm[it]);
            uint2 pq;
            pq.x = pack_bf2(v.x, v.y);
            pq.y = pack_bf2(v.z, v.w);
            int row = g_row0 + it * 32;
            int byte = row * 128 + g_f4c * 8;
            byte ^= (row & 7) << 4;
            *reinterpret_cast<uint2*>(reinterpret_cast<char*>(gB) + byte) = pq;
        }
        // issue next chunk's global loads (latency hides under MFMA below)
        if (ch < NCH - 1) {
            #pragma unroll
            for (int it = 0; it < 2; ++it)
                tReg[it] = *reinterpret_cast<const uint4*>(t_bf + (size_t)(t_row0 + it * 64) * (D / 2) + (ch + 1) * (BK / 2) + t_c8 * 4);
            #pragma unroll
            for (int it = 0; it < 4; ++it)
                gReg[it] = *reinterpret_cast<const float4*>(gal + (grow0 + g_row0 + it * 32) * D + (ch + 1) * BK + g_f4c * 4);
        }
        __syncthreads();   // LDS ready
        #pragma unroll
        for (int kh = 0; kh < 2; ++kh) {
            const int koff = kh * 64 + (lane >> 4) * 16;
            short8 a[2], bfr[4];
            #pragma unroll
            for (int m = 0; m < 2; ++m) {
                int row = wb * 32 + m * 16 + (lane & 15);
                int byte = row * 128 + koff;
                byte ^= (row & 7) << 4;
                a[m] = *reinterpret_cast<const short8*>(reinterpret_cast<const char*>(tA) + byte);
            }
            #pragma unroll
            for (int n = 0; n < 4; ++n) {
                int row = wg * 64 + n * 16 + (lane & 15);
                int byte = row * 128 + koff;
                byte ^= (row & 7) << 4;
                bfr[n] = *reinterpret_cast<const short8*>(reinterpret_cast<const char*>(gB) + byte);
            }
            #pragma unroll
            for (int m = 0; m < 2; ++m)
                #pragma unroll
                for (int n = 0; n < 4; ++n)
                    acc[m][n] = __builtin_amdgcn_mfma_f32_16x16x32_bf16(a[m], bfr[n], acc[m][n], 0, 0, 0);
        }
    }

    // gallery norms (thread's 4 g rows fixed across chunks)
    __syncthreads();
    #pragma unroll
    for (int it = 0; it < 4; ++it)
        normP[(g_row0 + it * 32) * 16 + g_f4c] = nrm[it];
    __syncthreads();
    if (tid < BG) {
        float s = 0.f;
        #pragma unroll
        for (int i = 0; i < 16; ++i) s += normP[tid * 16 + i];
        scaleS[tid] = 1.0f / fmaxf(sqrtf(s), 1e-12f);
    }
    __syncthreads();

    // top-5: 2 phases of 64 g; scan parallel over all 512 threads
    float rv[K]; int ri[K];
    #pragma unroll
    for (int k = 0; k < K; ++k) { rv[k] = -1e30f; ri[k] = 0x7fffffff; }

    for (int p = 0; p < 2; ++p) {
        if (wg == p) {
            #pragma unroll
            for (int n = 0; n < 4; ++n) {
                int gl = n * 16 + (lane & 15);
                float sc = scaleS[p * 64 + gl];
                #pragma unroll
                for (int m = 0; m < 2; ++m) {
                    int brow = wb * 32 + m * 16 + (lane >> 4) * 4;  // C/D: row=(l>>4)*4+r
                    #pragma unroll
                    for (int r = 0; r < 4; ++r)
                        scoresS[(brow + r) * SSTR + gl] = acc[m][n][r] * sc;
                }
            }
        }
        __syncthreads();
        const int brow = tid >> 2;
        const int gq = tid & 3;
        float lv[K]; int li[K];
        #pragma unroll
        for (int k = 0; k < K; ++k) { lv[k] = -1e30f; li[k] = 0x7fffffff; }
        #pragma unroll
        for (int i = 0; i < 16; ++i) {
            int g = gq * 16 + i;
            top5_insert(scoresS[brow * SSTR + g], blk * BG + p * 64 + g, lv, li);
        }
        // merge across the 4 threads of this b-row (same wave: masks 1, 2)
        {
            float ov[K]; int oi[K];
            #pragma unroll
            for (int k = 0; k < K; ++k) { ov[k] = __shfl_xor(lv[k], 1); oi[k] = __shfl_xor(li[k], 1); }
            #pragma unroll
            for (int k = 0; k < K; ++k) top5_insert(ov[k], oi[k], lv, li);
            #pragma unroll
            for (int k = 0; k < K; ++k) { ov[k] = __shfl_xor(lv[k], 2); oi[k] = __shfl_xor(li[k], 2); }
            #pragma unroll
            for (int k = 0; k < K; ++k) top5_insert(ov[k], oi[k], lv, li);
        }
        #pragma unroll
        for (int k = 0; k < K; ++k) top5_insert(lv[k], li[k], rv, ri);
        __syncthreads();
    }
    if ((tid & 3) == 0) {
        const int brow = tid >> 2;
        #pragma unroll
        for (int k = 0; k < K; ++k)
            partial[((size_t)brow * NBLK1 + blk) * K + k] = make_float2(rv[k], __int_as_float(ri[k]));
    }
}

// Kernel 2: merge 512 partial top-5 lists per batch row (coalesced layout
// [b][blk][k]) -> global top-5 indices. Block 0 inits the AND bitmap.
__global__ __launch_bounds__(512) void k2_merge(const float2* __restrict__ partial,
                                               int* __restrict__ top_idx,
                                               unsigned long long* __restrict__ mask64) {
    __shared__ float2 cand[NBLK1 * K];  // 20480 B
    const int b = blockIdx.x;
    const int p = threadIdx.x;
    if (b == 0 && p < (D / 64)) mask64[p] = ~0ull;

    float mv[K]; int mi[K];
    #pragma unroll
    for (int k = 0; k < K; ++k) {
        float2 c = partial[((size_t)b * NBLK1 + p) * K + k];
        mv[k] = c.x; mi[k] = __float_as_int(c.y);
        cand[p * K + k] = c;
    }
    __syncthreads();
    for (int s = NBLK1 / 2; s >= 1; s >>= 1) {
        if (p < s) {
            #pragma unroll
            for (int k = 0; k < K; ++k) {
                float2 c = cand[(p + s) * K + k];
                top5_insert(c.x, __float_as_int(c.y), mv, mi);
            }
            #pragma unroll
            for (int k = 0; k < K; ++k)
                cand[p * K + k] = make_float2(mv[k], __int_as_float(mi[k]));
        }
        __syncthreads();
    }
    if (p == 0) {
        #pragma unroll
        for (int k = 0; k < K; ++k) top_idx[b * K + k] = mi[k];
    }
}

// Kernel 3: rank-by-counting membership (bottom-m of |gal[row,c]*s_f[b,c]|),
// AND into bitmap. Per-row norms are positive constants -> ordering matches
// the reference's normalized products.
__global__ __launch_bounds__(512) void k3_member(const float* __restrict__ s_f,
                                                 const float* __restrict__ gal,
                                                 const int* __restrict__ top_idx,
                                                 unsigned long long* __restrict__ mask64) {
    __shared__ float pS[D];
    const int c = threadIdx.x;
    const int bk = blockIdx.x;
    const int b = bk / K;
    const int row = top_idx[bk];
    float pv = fabsf(gal[(size_t)row * D + c] * s_f[(size_t)b * D + c]);
    pS[c] = pv;
    __syncthreads();
    int cnt = 0;
    #pragma unroll 8
    for (int c2 = 0; c2 < D; ++c2) {
        float o = pS[c2];
        cnt += (o < pv || (o == pv && c2 < c)) ? 1 : 0;
    }
    bool member = cnt < M;
    unsigned long long bm = __ballot(member);
    if ((c & 63) == 0) atomicAnd(&mask64[c >> 6], bm);
}

// Kernel 4: mask[c] = zero_out[c] ? 0 : 1
__global__ __launch_bounds__(512) void k4_mask(const unsigned long long* __restrict__ mask64,
                                               float* __restrict__ out) {
    int c = threadIdx.x;
    out[c] = ((mask64[c >> 6] >> (c & 63)) & 1ull) ? 0.0f : 1.0f;
}

extern "C" void kernel_launch(void* const* d_in, const int* in_sizes, int n_in,
                              void* d_out, int out_size, void* d_ws, size_t ws_size,
                              hipStream_t stream) {
    (void)in_sizes; (void)n_in; (void)out_size; (void)ws_size;
    const float* s_f = (const float*)d_in[0];
    const float* t_f = (const float*)d_in[1];
    const float* gal = (const float*)d_in[2];
    float* out = (float*)d_out;

    char* ws = (char*)d_ws;
    size_t off_tbf = 0;
    size_t sz_tbf = (size_t)B * D * 2;                            // 131072 B
    size_t off_partial = off_tbf + sz_tbf;
    size_t sz_partial = (size_t)NBLK1 * B * K * sizeof(float2);   // 2,621,440 B
    size_t off_topidx = off_partial + sz_partial;
    size_t sz_topidx = (size_t)B * K * sizeof(int);
    size_t off_mask = off_topidx + sz_topidx;

    unsigned int* t_bf = (unsigned int*)(ws + off_tbf);
    float2* partial = (float2*)(ws + off_partial);
    int* top_idx = (int*)(ws + off_topidx);
    unsigned long long* mask64 = (unsigned long long*)(ws + off_mask);

    hipLaunchKernelGGL(k0_cvt_t, dim3(B * D / 4 / 256), dim3(256), 0, stream, t_f, t_bf);
    hipLaunchKernelGGL(k1_sims_topk, dim3(NBLK1), dim3(512), 0, stream, t_bf, gal, partial);
    hipLaunchKernelGGL(k2_merge, dim3(B), dim3(512), 0, stream, partial, top_idx, mask64);
    hipLaunchKernelGGL(k3_member, dim3(B * K), dim3(512), 0, stream, s_f, gal, top_idx, mask64);
    hipLaunchKernelGGL(k4_mask, dim3(1), dim3(512), 0, stream, mask64, out);
}

// Round 4
// 156.717 us; speedup vs baseline: 3.5436x; 1.1222x over previous
//
#include <hip/hip_runtime.h>

#define B 128
#define N 65536
#define D 512
#define K 5
#define M 256              // D * RATIO
#define GPB 128            // gallery rows per block (kernel1)
#define NBLK1 (N / GPB)    // 512 blocks
#define CHG 16             // g rows per chunk
#define NCHK (GPB / CHG)   // 8

typedef __attribute__((ext_vector_type(8))) short short8;
typedef __attribute__((ext_vector_type(4))) float f32x4;

// pack two fp32 -> one u32 of 2 bf16 (truncation) via v_perm_b32.
__device__ __forceinline__ unsigned int pack_bf2(float lo, float hi) {
    return __builtin_amdgcn_perm(__float_as_uint(hi), __float_as_uint(lo), 0x07060302u);
}

__device__ __forceinline__ void top5_insert(float v, int gi, float tv[K], int ti[K]) {
    // descending by value, ties broken by lower index (matches lax.top_k)
    if (v > tv[K - 1] || (v == tv[K - 1] && gi < ti[K - 1])) {
        tv[K - 1] = v; ti[K - 1] = gi;
        #pragma unroll
        for (int k = K - 1; k > 0; --k) {
            bool sw = (tv[k] > tv[k - 1]) || (tv[k] == tv[k - 1] && ti[k] < ti[k - 1]);
            if (sw) {
                float fv = tv[k]; tv[k] = tv[k - 1]; tv[k - 1] = fv;
                int fi = ti[k]; ti[k] = ti[k - 1]; ti[k - 1] = fi;
            }
        }
    }
}

// Kernel 0: convert t_f (128x512 fp32) -> bf16 once. L2-resident thereafter.
__global__ __launch_bounds__(256) void k0_cvt_t(const float* __restrict__ t_f,
                                                unsigned int* __restrict__ t_bf) {
    int i = blockIdx.x * 256 + threadIdx.x;   // float4 index, 16384 total
    float4 v = reinterpret_cast<const float4*>(t_f)[i];
    uint2 p;
    p.x = pack_bf2(v.x, v.y);
    p.y = pack_bf2(v.z, v.w);
    reinterpret_cast<uint2*>(t_bf)[i] = p;
}

// Kernel 1: block = 8 waves x 512 thr, covers ALL 128 b-rows x 128 g-rows.
// Wave w owns b-rows [16w,16w+16): A-fragments resident in 64 VGPRs (loaded
// once from t_bf). Gallery staged per 16-g chunk into LDS [ks][row][32bf16]
// (lane-contiguous writes + contiguous 1KB fragment reads: conflict-free),
// double-buffered, ONE barrier per chunk, loads issued before compute (T14).
// Top-5 kept per-lane with g-index packed into low 8 mantissa bits (3e-5
// perturbation << bf16 score noise), shfl_xor merge at end.
__global__ __launch_bounds__(512) void k1_sims_topk(const unsigned short* __restrict__ t_bf,
                                                    const float* __restrict__ gal,
                                                    float2* __restrict__ partial) {
    __shared__ unsigned short gLds[2][CHG * D];   // 2 x 16384 B
    __shared__ float normP[2][8][16];             // 1024 B

    const int tid = threadIdx.x;
    const int blk = blockIdx.x;
    const int lane = tid & 63;
    const int w = tid >> 6;
    const int l15 = lane & 15;
    const int l4 = lane >> 4;

    // A fragments: wave's 16 b-rows (row = l15), full K. 64 VGPRs.
    short8 afr[16];
    {
        const unsigned short* tp = t_bf + (size_t)(w * 16 + l15) * D + l4 * 8;
        #pragma unroll
        for (int ks = 0; ks < 16; ++ks)
            afr[ks] = *reinterpret_cast<const short8*>(tp + ks * 32);
    }

    // packed top-5 lists: lst[r] for b-row w*16 + l4*4 + r, over g ≡ l15 (mod 16)
    float lst[4][K];
    #pragma unroll
    for (int r = 0; r < 4; ++r)
        #pragma unroll
        for (int k = 0; k < K; ++k) lst[r][k] = -1e30f;

    // staging geometry: thread covers g-row (lane>>2), k-cols {w*32, 256+w*32} + (lane&3)*8
    const int srow = lane >> 2;        // 0..15
    const int scol = w * 32 + (lane & 3) * 8;
    const float* gsrc0 = gal + ((size_t)blk * GPB + srow) * D + scol;

    float4 st[4];
    #pragma unroll
    for (int i = 0; i < 2; ++i) {
        st[i]     = *reinterpret_cast<const float4*>(gsrc0 + i * 4);
        st[i + 2] = *reinterpret_cast<const float4*>(gsrc0 + 256 + i * 4);
    }
    // stage chunk 0 into buf 0
    {
        float nr = 0.f;
        #pragma unroll
        for (int i = 0; i < 4; ++i) {
            nr = fmaf(st[i].x, st[i].x, nr);
            nr = fmaf(st[i].y, st[i].y, nr);
            nr = fmaf(st[i].z, st[i].z, nr);
            nr = fmaf(st[i].w, st[i].w, nr);
        }
        char* LB = reinterpret_cast<char*>(&gLds[0][0]);
        uint4 q0, q1;
        q0.x = pack_bf2(st[0].x, st[0].y); q0.y = pack_bf2(st[0].z, st[0].w);
        q0.z = pack_bf2(st[1].x, st[1].y); q0.w = pack_bf2(st[1].z, st[1].w);
        q1.x = pack_bf2(st[2].x, st[2].y); q1.y = pack_bf2(st[2].z, st[2].w);
        q1.z = pack_bf2(st[3].x, st[3].y); q1.w = pack_bf2(st[3].z, st[3].w);
        *reinterpret_cast<uint4*>(LB + tid * 16) = q0;
        *reinterpret_cast<uint4*>(LB + 8192 + tid * 16) = q1;
        nr += __shfl_xor(nr, 1);
        nr += __shfl_xor(nr, 2);
        if ((lane & 3) == 0) normP[0][w][srow] = nr;
    }
    __syncthreads();

    for (int c = 0; c < NCHK; ++c) {
        const int buf = c & 1;
        // issue next chunk's global loads (hide latency under MFMA)
        if (c + 1 < NCHK) {
            const float* gs = gsrc0 + (size_t)(c + 1) * CHG * D;
            #pragma unroll
            for (int i = 0; i < 2; ++i) {
                st[i]     = *reinterpret_cast<const float4*>(gs + i * 4);
                st[i + 2] = *reinterpret_cast<const float4*>(gs + 256 + i * 4);
            }
        }
        // compute chunk c
        f32x4 acc = (f32x4)0.0f;
        const unsigned short* Lr = &gLds[buf][0];
        const int foff = l15 * 32 + l4 * 8;    // ushort offset within k-slice
        #pragma unroll
        for (int ks = 0; ks < 16; ++ks) {
            short8 bf = *reinterpret_cast<const short8*>(Lr + ks * 512 + foff);
            acc = __builtin_amdgcn_mfma_f32_16x16x32_bf16(afr[ks], bf, acc, 0, 0, 0);
        }
        float sml = 0.f;
        #pragma unroll
        for (int w2 = 0; w2 < 8; ++w2) sml += normP[buf][w2][l15];
        float sc = 1.0f / fmaxf(sqrtf(sml), 1e-12f);
        unsigned meta = (unsigned)(c * CHG + l15);   // local g-index, 0..127
        #pragma unroll
        for (int r = 0; r < 4; ++r) {
            float s = acc[r] * sc;
            float sp = __uint_as_float((__float_as_uint(s) & 0xFFFFFF00u) | meta);
            if (sp > lst[r][K - 1]) {
                lst[r][K - 1] = sp;
                #pragma unroll
                for (int k = K - 1; k > 0; --k)
                    if (lst[r][k] > lst[r][k - 1]) {
                        float t2 = lst[r][k]; lst[r][k] = lst[r][k - 1]; lst[r][k - 1] = t2;
                    }
            }
        }
        // stage chunk c+1 into the other buffer
        if (c + 1 < NCHK) {
            float nr = 0.f;
            #pragma unroll
            for (int i = 0; i < 4; ++i) {
                nr = fmaf(st[i].x, st[i].x, nr);
                nr = fmaf(st[i].y, st[i].y, nr);
                nr = fmaf(st[i].z, st[i].z, nr);
                nr = fmaf(st[i].w, st[i].w, nr);
            }
            char* LB = reinterpret_cast<char*>(&gLds[buf ^ 1][0]);
            uint4 q0, q1;
            q0.x = pack_bf2(st[0].x, st[0].y); q0.y = pack_bf2(st[0].z, st[0].w);
            q0.z = pack_bf2(st[1].x, st[1].y); q0.w = pack_bf2(st[1].z, st[1].w);
            q1.x = pack_bf2(st[2].x, st[2].y); q1.y = pack_bf2(st[2].z, st[2].w);
            q1.z = pack_bf2(st[3].x, st[3].y); q1.w = pack_bf2(st[3].z, st[3].w);
            *reinterpret_cast<uint4*>(LB + tid * 16) = q0;
            *reinterpret_cast<uint4*>(LB + 8192 + tid * 16) = q1;
            nr += __shfl_xor(nr, 1);
            nr += __shfl_xor(nr, 2);
            if ((lane & 3) == 0) normP[buf ^ 1][w][srow] = nr;
        }
        __syncthreads();
    }

    // merge the 16 g-residues within each l4 group (lists stay packed)
    #pragma unroll
    for (int mk = 1; mk <= 8; mk <<= 1) {
        #pragma unroll
        for (int r = 0; r < 4; ++r) {
            float inc[K];
            #pragma unroll
            for (int k = 0; k < K; ++k) inc[k] = __shfl_xor(lst[r][k], mk);
            #pragma unroll
            for (int k = 0; k < K; ++k) {
                if (inc[k] > lst[r][K - 1]) {
                    lst[r][K - 1] = inc[k];
                    #pragma unroll
                    for (int q = K - 1; q > 0; --q)
                        if (lst[r][q] > lst[r][q - 1]) {
                            float t2 = lst[r][q]; lst[r][q] = lst[r][q - 1]; lst[r][q - 1] = t2;
                        }
                }
            }
        }
    }

    // writers: lane l15==r writes list r (all 16 lanes of a group converged)
    #pragma unroll
    for (int rr = 0; rr < 4; ++rr) {
        if (l15 == rr) {
            int b = w * 16 + l4 * 4 + rr;
            #pragma unroll
            for (int k = 0; k < K; ++k) {
                unsigned sp = __float_as_uint(lst[rr][k]);
                int g = blk * GPB + (int)(sp & 0xFFu);
                partial[((size_t)b * NBLK1 + blk) * K + k] = make_float2(lst[rr][k], __int_as_float(g));
            }
        }
    }
}

// Kernel 2: merge 512 partial top-5 lists per batch row (coalesced [b][blk][k])
// -> global top-5 indices. Block 0 inits the AND bitmap.
__global__ __launch_bounds__(512) void k2_merge(const float2* __restrict__ partial,
                                               int* __restrict__ top_idx,
                                               unsigned long long* __restrict__ mask64) {
    __shared__ float2 cand[NBLK1 * K];  // 20480 B
    const int b = blockIdx.x;
    const int p = threadIdx.x;
    if (b == 0 && p < (D / 64)) mask64[p] = ~0ull;

    float mv[K]; int mi[K];
    #pragma unroll
    for (int k = 0; k < K; ++k) {
        float2 c = partial[((size_t)b * NBLK1 + p) * K + k];
        mv[k] = c.x; mi[k] = __float_as_int(c.y);
        cand[p * K + k] = c;
    }
    __syncthreads();
    for (int s = NBLK1 / 2; s >= 1; s >>= 1) {
        if (p < s) {
            #pragma unroll
            for (int k = 0; k < K; ++k) {
                float2 c = cand[(p + s) * K + k];
                top5_insert(c.x, __float_as_int(c.y), mv, mi);
            }
            #pragma unroll
            for (int k = 0; k < K; ++k)
                cand[p * K + k] = make_float2(mv[k], __int_as_float(mi[k]));
        }
        __syncthreads();
    }
    if (p == 0) {
        #pragma unroll
        for (int k = 0; k < K; ++k) top_idx[b * K + k] = mi[k];
    }
}

// Kernel 3: rank-by-counting membership (bottom-m of |gal[row,c]*s_f[b,c]|;
// per-row norms are positive constants -> ordering matches the reference's
// normalized products), AND into bitmap.
__global__ __launch_bounds__(512) void k3_member(const float* __restrict__ s_f,
                                                 const float* __restrict__ gal,
                                                 const int* __restrict__ top_idx,
                                                 unsigned long long* __restrict__ mask64) {
    __shared__ float pS[D];
    const int c = threadIdx.x;
    const int bk = blockIdx.x;
    const int b = bk / K;
    const int row = top_idx[bk];
    float pv = fabsf(gal[(size_t)row * D + c] * s_f[(size_t)b * D + c]);
    pS[c] = pv;
    __syncthreads();
    int cnt = 0;
    #pragma unroll 8
    for (int c2 = 0; c2 < D; ++c2) {
        float o = pS[c2];
        cnt += (o < pv || (o == pv && c2 < c)) ? 1 : 0;
    }
    bool member = cnt < M;
    unsigned long long bm = __ballot(member);
    if ((c & 63) == 0) atomicAnd(&mask64[c >> 6], bm);
}

// Kernel 4: mask[c] = zero_out[c] ? 0 : 1
__global__ __launch_bounds__(512) void k4_mask(const unsigned long long* __restrict__ mask64,
                                               float* __restrict__ out) {
    int c = threadIdx.x;
    out[c] = ((mask64[c >> 6] >> (c & 63)) & 1ull) ? 0.0f : 1.0f;
}

extern "C" void kernel_launch(void* const* d_in, const int* in_sizes, int n_in,
                              void* d_out, int out_size, void* d_ws, size_t ws_size,
                              hipStream_t stream) {
    (void)in_sizes; (void)n_in; (void)out_size; (void)ws_size;
    const float* s_f = (const float*)d_in[0];
    const float* t_f = (const float*)d_in[1];
    const float* gal = (const float*)d_in[2];
    float* out = (float*)d_out;

    char* ws = (char*)d_ws;
    size_t off_tbf = 0;
    size_t sz_tbf = (size_t)B * D * 2;                            // 131072 B
    size_t off_partial = off_tbf + sz_tbf;
    size_t sz_partial = (size_t)NBLK1 * B * K * sizeof(float2);   // 2,621,440 B
    size_t off_topidx = off_partial + sz_partial;
    size_t sz_topidx = (size_t)B * K * sizeof(int);
    size_t off_mask = off_topidx + sz_topidx;

    unsigned int* t_bf = (unsigned int*)(ws + off_tbf);
    float2* partial = (float2*)(ws + off_partial);
    int* top_idx = (int*)(ws + off_topidx);
    unsigned long long* mask64 = (unsigned long long*)(ws + off_mask);

    hipLaunchKernelGGL(k0_cvt_t, dim3(B * D / 4 / 256), dim3(256), 0, stream, t_f, t_bf);
    hipLaunchKernelGGL(k1_sims_topk, dim3(NBLK1), dim3(512), 0, stream,
                       (const unsigned short*)t_bf, gal, partial);
    hipLaunchKernelGGL(k2_merge, dim3(B), dim3(512), 0, stream, partial, top_idx, mask64);
    hipLaunchKernelGGL(k3_member, dim3(B * K), dim3(512), 0, stream, s_f, gal, top_idx, mask64);
    hipLaunchKernelGGL(k4_mask, dim3(1), dim3(512), 0, stream, mask64, out);
}

// Round 5
// 155.856 us; speedup vs baseline: 3.5632x; 1.0055x over previous
//
#include <hip/hip_runtime.h>

#define B 128
#define N 65536
#define D 512
#define K 5
#define M 256              // D * RATIO
#define GPB 128            // gallery rows per block (kernel1)
#define NBLK1 (N / GPB)    // 512 blocks
#define CHG 16             // g rows per chunk
#define NCHK (GPB / CHG)   // 8

typedef __attribute__((ext_vector_type(8))) short short8;
typedef __attribute__((ext_vector_type(4))) float f32x4;

// pack two fp32 -> one u32 of 2 bf16 (truncation) via v_perm_b32.
__device__ __forceinline__ unsigned int pack_bf2(float lo, float hi) {
    return __builtin_amdgcn_perm(__float_as_uint(hi), __float_as_uint(lo), 0x07060302u);
}

__device__ __forceinline__ void top5_insert(float v, int gi, float tv[K], int ti[K]) {
    // descending by value, ties broken by lower index (matches lax.top_k)
    if (v > tv[K - 1] || (v == tv[K - 1] && gi < ti[K - 1])) {
        tv[K - 1] = v; ti[K - 1] = gi;
        #pragma unroll
        for (int k = K - 1; k > 0; --k) {
            bool sw = (tv[k] > tv[k - 1]) || (tv[k] == tv[k - 1] && ti[k] < ti[k - 1]);
            if (sw) {
                float fv = tv[k]; tv[k] = tv[k - 1]; tv[k - 1] = fv;
                int fi = ti[k]; ti[k] = ti[k - 1]; ti[k - 1] = fi;
            }
        }
    }
}

// Kernel 1: bf16 MFMA sims. Block = 8 waves x 512 thr, all 128 b x 128 g rows.
// Wave w owns b-rows [16w,16w+16): A-fragments resident in 64 VGPRs, converted
// from t_f fp32 in the prologue (t_f is L2/L3-resident, 256 KB). Gallery staged
// per 16-g chunk into LDS [ks][row][32bf16] (lane-contiguous writes, contiguous
// 1KB wave reads: conflict-free), double-buffered, one barrier per chunk,
// global loads issued before compute (T14). Per-lane packed top-5 (g-index in
// low 8 mantissa bits), shfl_xor merge at end. __launch_bounds__(512,1): allow
// up to 256 VGPR -- R3/R4's scratch spills were the latency+occupancy killer.
__global__ __launch_bounds__(512, 1) void k1_sims_topk(const float* __restrict__ t_f,
                                                       const float* __restrict__ gal,
                                                       float2* __restrict__ partial,
                                                       unsigned long long* __restrict__ mask64) {
    __shared__ unsigned short gLds[2][CHG * D];   // 2 x 16384 B
    __shared__ float normP[2][CHG][8];            // 1024 B

    const int tid = threadIdx.x;
    const int blk = blockIdx.x;
    const int lane = tid & 63;
    const int w = tid >> 6;
    const int l15 = lane & 15;
    const int l4 = lane >> 4;

    if (blk == 0 && tid < (D / 64)) mask64[tid] = ~0ull;   // init AND bitmap (k23 runs after)

    // staging geometry: thread covers g-row (lane>>2), k-cols {w*32, 256+w*32} + (lane&3)*8
    const int srow = lane >> 2;        // 0..15
    const int scol = w * 32 + (lane & 3) * 8;
    const float* gsrc0 = gal + ((size_t)blk * GPB + srow) * D + scol;

    // issue chunk-0 gallery loads first
    float4 st[4];
    #pragma unroll
    for (int i = 0; i < 2; ++i) {
        st[i]     = *reinterpret_cast<const float4*>(gsrc0 + i * 4);
        st[i + 2] = *reinterpret_cast<const float4*>(gsrc0 + 256 + i * 4);
    }

    // A fragments: wave's 16 b-rows (row = l15), converted fp32->bf16. 64 VGPRs.
    short8 afr[16];
    {
        const float* tp = t_f + (size_t)(w * 16 + l15) * D + l4 * 8;
        #pragma unroll
        for (int ks = 0; ks < 16; ++ks) {
            float4 a0 = *reinterpret_cast<const float4*>(tp + ks * 32);
            float4 a1 = *reinterpret_cast<const float4*>(tp + ks * 32 + 4);
            uint4 q;
            q.x = pack_bf2(a0.x, a0.y); q.y = pack_bf2(a0.z, a0.w);
            q.z = pack_bf2(a1.x, a1.y); q.w = pack_bf2(a1.z, a1.w);
            afr[ks] = *reinterpret_cast<short8*>(&q);
        }
    }

    // packed top-5 lists: lst[r] for b-row w*16 + l4*4 + r, over g ≡ l15 (mod 16)
    float lst[4][K];
    #pragma unroll
    for (int r = 0; r < 4; ++r)
        #pragma unroll
        for (int k = 0; k < K; ++k) lst[r][k] = -1e30f;

    // stage chunk 0 into buf 0
    {
        float nr = 0.f;
        #pragma unroll
        for (int i = 0; i < 4; ++i) {
            nr = fmaf(st[i].x, st[i].x, nr);
            nr = fmaf(st[i].y, st[i].y, nr);
            nr = fmaf(st[i].z, st[i].z, nr);
            nr = fmaf(st[i].w, st[i].w, nr);
        }
        char* LB = reinterpret_cast<char*>(&gLds[0][0]);
        uint4 q0, q1;
        q0.x = pack_bf2(st[0].x, st[0].y); q0.y = pack_bf2(st[0].z, st[0].w);
        q0.z = pack_bf2(st[1].x, st[1].y); q0.w = pack_bf2(st[1].z, st[1].w);
        q1.x = pack_bf2(st[2].x, st[2].y); q1.y = pack_bf2(st[2].z, st[2].w);
        q1.z = pack_bf2(st[3].x, st[3].y); q1.w = pack_bf2(st[3].z, st[3].w);
        *reinterpret_cast<uint4*>(LB + tid * 16) = q0;
        *reinterpret_cast<uint4*>(LB + 8192 + tid * 16) = q1;
        nr += __shfl_xor(nr, 1);
        nr += __shfl_xor(nr, 2);
        if ((lane & 3) == 0) normP[0][srow][w] = nr;
    }
    __syncthreads();

    for (int c = 0; c < NCHK; ++c) {
        const int buf = c & 1;
        // issue next chunk's global loads (hide latency under MFMA)
        if (c + 1 < NCHK) {
            const float* gs = gsrc0 + (size_t)(c + 1) * CHG * D;
            #pragma unroll
            for (int i = 0; i < 2; ++i) {
                st[i]     = *reinterpret_cast<const float4*>(gs + i * 4);
                st[i + 2] = *reinterpret_cast<const float4*>(gs + 256 + i * 4);
            }
        }
        // compute chunk c
        f32x4 acc = (f32x4)0.0f;
        const unsigned short* Lr = &gLds[buf][0];
        const int foff = l15 * 32 + l4 * 8;    // ushort offset within k-slice
        #pragma unroll
        for (int ks = 0; ks < 16; ++ks) {
            short8 bf = *reinterpret_cast<const short8*>(Lr + ks * 512 + foff);
            acc = __builtin_amdgcn_mfma_f32_16x16x32_bf16(afr[ks], bf, acc, 0, 0, 0);
        }
        // per-g scale = rsqrt(sum of 8 wave-partials), vector reads
        f32x4 n0 = *reinterpret_cast<const f32x4*>(&normP[buf][l15][0]);
        f32x4 n1 = *reinterpret_cast<const f32x4*>(&normP[buf][l15][4]);
        float sml = (n0[0] + n0[1]) + (n0[2] + n0[3]) + (n1[0] + n1[1]) + (n1[2] + n1[3]);
        float sc = rsqrtf(sml);
        unsigned meta = (unsigned)(c * CHG + l15);   // local g-index, 0..127
        #pragma unroll
        for (int r = 0; r < 4; ++r) {
            float s = acc[r] * sc;
            float sp = __uint_as_float((__float_as_uint(s) & 0xFFFFFF00u) | meta);
            if (sp > lst[r][K - 1]) {
                lst[r][K - 1] = sp;
                #pragma unroll
                for (int k = K - 1; k > 0; --k)
                    if (lst[r][k] > lst[r][k - 1]) {
                        float t2 = lst[r][k]; lst[r][k] = lst[r][k - 1]; lst[r][k - 1] = t2;
                    }
            }
        }
        // stage chunk c+1 into the other buffer
        if (c + 1 < NCHK) {
            float nr = 0.f;
            #pragma unroll
            for (int i = 0; i < 4; ++i) {
                nr = fmaf(st[i].x, st[i].x, nr);
                nr = fmaf(st[i].y, st[i].y, nr);
                nr = fmaf(st[i].z, st[i].z, nr);
                nr = fmaf(st[i].w, st[i].w, nr);
            }
            char* LB = reinterpret_cast<char*>(&gLds[buf ^ 1][0]);
            uint4 q0, q1;
            q0.x = pack_bf2(st[0].x, st[0].y); q0.y = pack_bf2(st[0].z, st[0].w);
            q0.z = pack_bf2(st[1].x, st[1].y); q0.w = pack_bf2(st[1].z, st[1].w);
            q1.x = pack_bf2(st[2].x, st[2].y); q1.y = pack_bf2(st[2].z, st[2].w);
            q1.z = pack_bf2(st[3].x, st[3].y); q1.w = pack_bf2(st[3].z, st[3].w);
            *reinterpret_cast<uint4*>(LB + tid * 16) = q0;
            *reinterpret_cast<uint4*>(LB + 8192 + tid * 16) = q1;
            nr += __shfl_xor(nr, 1);
            nr += __shfl_xor(nr, 2);
            if ((lane & 3) == 0) normP[buf ^ 1][srow][w] = nr;
        }
        __syncthreads();
    }

    // merge the 16 g-residues within each l4 group (lists stay packed)
    #pragma unroll
    for (int mk = 1; mk <= 8; mk <<= 1) {
        #pragma unroll
        for (int r = 0; r < 4; ++r) {
            float inc[K];
            #pragma unroll
            for (int k = 0; k < K; ++k) inc[k] = __shfl_xor(lst[r][k], mk);
            #pragma unroll
            for (int k = 0; k < K; ++k) {
                if (inc[k] > lst[r][K - 1]) {
                    lst[r][K - 1] = inc[k];
                    #pragma unroll
                    for (int q = K - 1; q > 0; --q)
                        if (lst[r][q] > lst[r][q - 1]) {
                            float t2 = lst[r][q]; lst[r][q] = lst[r][q - 1]; lst[r][q - 1] = t2;
                        }
                }
            }
        }
    }

    // writers: lane l15==r writes list r (all 16 lanes of a group converged)
    #pragma unroll
    for (int rr = 0; rr < 4; ++rr) {
        if (l15 == rr) {
            int b = w * 16 + l4 * 4 + rr;
            #pragma unroll
            for (int k = 0; k < K; ++k) {
                unsigned sp = __float_as_uint(lst[rr][k]);
                int g = blk * GPB + (int)(sp & 0xFFu);
                partial[((size_t)b * NBLK1 + blk) * K + k] = make_float2(lst[rr][k], __int_as_float(g));
            }
        }
    }
}

// Kernel 23 (fused merge + membership): block b merges its 512 partial top-5
// lists -> top-5 global rows, then for each of the K rows computes the
// bottom-m membership of |gal[row,c]*s_f[b,c]| (per-row norms are positive
// constants -> same ordering as the reference's normalized products) and ANDs
// the block's 512-bit mask into the global bitmap.
__global__ __launch_bounds__(512) void k23_merge_member(const float2* __restrict__ partial,
                                                        const float* __restrict__ s_f,
                                                        const float* __restrict__ gal,
                                                        unsigned long long* __restrict__ mask64) {
    __shared__ float2 cand[NBLK1 * K];          // 20480 B
    __shared__ int idxS[K];
    __shared__ float pS[D];
    __shared__ unsigned long long andW[D / 64];

    const int b = blockIdx.x;
    const int p = threadIdx.x;
    if (p < (D / 64)) andW[p] = ~0ull;

    float mv[K]; int mi[K];
    #pragma unroll
    for (int k = 0; k < K; ++k) {
        float2 c = partial[((size_t)b * NBLK1 + p) * K + k];
        mv[k] = c.x; mi[k] = __float_as_int(c.y);
        cand[p * K + k] = c;
    }
    __syncthreads();
    for (int s = NBLK1 / 2; s >= 1; s >>= 1) {
        if (p < s) {
            #pragma unroll
            for (int k = 0; k < K; ++k) {
                float2 c = cand[(p + s) * K + k];
                top5_insert(c.x, __float_as_int(c.y), mv, mi);
            }
            #pragma unroll
            for (int k = 0; k < K; ++k)
                cand[p * K + k] = make_float2(mv[k], __int_as_float(mi[k]));
        }
        __syncthreads();
    }
    if (p == 0) {
        #pragma unroll
        for (int k = 0; k < K; ++k) idxS[k] = mi[k];
    }
    __syncthreads();

    const float sv = s_f[(size_t)b * D + p];
    for (int k = 0; k < K; ++k) {
        const int row = idxS[k];
        float pv = fabsf(gal[(size_t)row * D + p] * sv);
        __syncthreads();          // guard pS reuse from previous iteration
        pS[p] = pv;
        __syncthreads();
        int cnt = 0;
        #pragma unroll 8
        for (int c2 = 0; c2 < D; ++c2) {
            float o = pS[c2];
            cnt += (o < pv || (o == pv && c2 < p)) ? 1 : 0;
        }
        unsigned long long bm = __ballot(cnt < M);
        if ((p & 63) == 0) andW[p >> 6] &= bm;
    }
    __syncthreads();
    if (p < (D / 64)) atomicAnd(&mask64[p], andW[p]);
}

// Kernel 4: mask[c] = zero_out[c] ? 0 : 1
__global__ __launch_bounds__(512) void k4_mask(const unsigned long long* __restrict__ mask64,
                                               float* __restrict__ out) {
    int c = threadIdx.x;
    out[c] = ((mask64[c >> 6] >> (c & 63)) & 1ull) ? 0.0f : 1.0f;
}

extern "C" void kernel_launch(void* const* d_in, const int* in_sizes, int n_in,
                              void* d_out, int out_size, void* d_ws, size_t ws_size,
                              hipStream_t stream) {
    (void)in_sizes; (void)n_in; (void)out_size; (void)ws_size;
    const float* s_f = (const float*)d_in[0];
    const float* t_f = (const float*)d_in[1];
    const float* gal = (const float*)d_in[2];
    float* out = (float*)d_out;

    char* ws = (char*)d_ws;
    size_t off_partial = 0;
    size_t sz_partial = (size_t)NBLK1 * B * K * sizeof(float2);   // 2,621,440 B
    size_t off_mask = off_partial + sz_partial;

    float2* partial = (float2*)(ws + off_partial);
    unsigned long long* mask64 = (unsigned long long*)(ws + off_mask);

    hipLaunchKernelGGL(k1_sims_topk, dim3(NBLK1), dim3(512), 0, stream, t_f, gal, partial, mask64);
    hipLaunchKernelGGL(k23_merge_member, dim3(B), dim3(512), 0, stream, partial, s_f, gal, mask64);
    hipLaunchKernelGGL(k4_mask, dim3(1), dim3(512), 0, stream, mask64, out);
}